// Round 20
// baseline (108.594 us; speedup 1.0000x reference)
//
#include <hip/hip_runtime.h>
#include <hip/hip_bf16.h>
#include <stdint.h>

// RadianceNetwork: 256 independent channel MLPs, B=64.
//   x  = concat(ue[3], view[3], feat[128], nid[1])  -> [64, 135]
//   h1 = relu(x @ W1[c] + b1[c])                    -> [64, 256]
//   h2 = relu(h1 @ W2[c] + b2[c])                   -> [64, 256]
//   o  = h2 @ W3[c] + b3[c]                         -> [64, 816]
// OUTPUT: real components only, fp32 [64][256][408] (R0-R5 forensics).
//
// Campaign invariant: only 2-independent-blocks/CU ever raised delivered BW
// (R8/R9: 5.9-6.8 TB/s, but 2x duplicated weights); all 1-block/CU variants
// deliver ~4.1 TB/s regardless of pipeline (R11-R19, 84-94us). R20: split
// channels by N -> zero duplication AND 2 blocks/CU. Cross-layer K-dependency
// resolved by 3 chained kernels (stream order = global sync); h1/h2 through
// d_ws as bf16 (8.4 MB, L3-resident). Each kernel keeps the R16/R19 pipeline:
// global_load_lds DMA, 3-slot ring, 2 tiles in flight, raw s_barrier +
// graduated counted vmcnt (never draining mid-chunk).
// Blocks: 512 thr, 8 waves; wave w owns n-tile w (16 cols) x 64 rows (MT=4).

#define NCH    256
#define BATCH  64
#define MT     4
#define IN_K   135
#define HID    256
#define OUTN   816
#define OUTS   408
#define XPITCHB 336   // x row bytes (168 bf16; zero-padded k in [135,168))
#define HROWB   512   // h row bytes (256 bf16, XOR-swizzled in LDS)
#define BLOCK  512
#define SLOTB  16384  // ring slot: 32 k-rows x 128 n-cols fp32
#define WRINGB (3 * SLOTB)

typedef __bf16 bf16x8 __attribute__((ext_vector_type(8)));
typedef float  f32x4  __attribute__((ext_vector_type(4)));
typedef const __attribute__((address_space(1))) void* gas_t;
typedef __attribute__((address_space(3))) void*       las_t;

// One N-chunk (128 or 48 cols at nc0) of one layer; k over KT 32-tiles.
// MFMA 16x16x32 bf16 (m89 layouts). Ring slot (DMA, linear): fp32
// [k 0..31][n 0..NCW-1], pitch NCW*4. Wave w: 2 instrs/tile covering k-rows
// 4w..4w+3 (NCW=128: 64 lanes x 16B = 1KB contiguous; NCW=48: 24 lanes).
template<int K, int KT, int NSRC, int NCW, bool ASWZ, bool RELU>
__device__ __forceinline__ void chunk_pipe(
    const char*  __restrict__ A,     // LDS activations (x or swizzled h)
    const float* __restrict__ Wg,    // [K][NSRC] weights, channel base
    const float* __restrict__ bg,    // bias, channel base
    __bf16*      __restrict__ hg,    // global h out, channel base (RELU path)
    float*       __restrict__ outg,  // global out, channel base (L3 path)
    unsigned long long out_sz, int nc0,
    char* __restrict__ wslots, int wave, int lane)
{
  constexpr int PITCH = NCW * 4;
  const int col = lane & 15;
  const int g   = lane >> 4;
  const bool active = (wave * 16) < NCW;

  // chunk entry: all waves done with previous chunk's slots
  asm volatile("s_waitcnt lgkmcnt(0)" ::: "memory");
  asm volatile("s_barrier" ::: "memory");

  auto issue = [&](int t) {
    if (t < KT) {
      char* base = wslots + (t % 3) * SLOTB;
#pragma unroll
      for (int j = 0; j < 2; ++j) {
        if (NCW == 128) {
          const int r = 4 * wave + 2 * j + (lane >> 5);
          int k = t * 32 + r;
          if (K % 32 != 0) k = (k < K) ? k : (K - 1);  // L1 tail: A is zero there
          const float* src = Wg + (size_t)k * NSRC + nc0 + (size_t)(lane & 31) * 4;
          char* dst = base + (4 * wave + 2 * j) * 512 + lane * 16;
          __builtin_amdgcn_global_load_lds((gas_t)src, (las_t)dst, 16, 0, 0);
        } else {  // NCW == 48: 24 lanes cover 2 rows x 192B
          if (lane < 24) {
            const int r = 4 * wave + 2 * j + (lane >= 12 ? 1 : 0);
            const int k = t * 32 + r;
            const float* src = Wg + (size_t)k * NSRC + nc0 +
                               (size_t)(lane % 12) * 4;
            char* dst = base + (4 * wave + 2 * j) * PITCH + lane * 16;
            __builtin_amdgcn_global_load_lds((gas_t)src, (las_t)dst, 16, 0, 0);
          }
        }
      }
    }
  };

  issue(0); issue(1);                // 2 tiles (4 instrs/wave) in flight

  f32x4 acc[MT] = {};

#pragma unroll
  for (int kt = 0; kt < KT; ++kt) {
    if (kt < KT - 1) asm volatile("s_waitcnt vmcnt(2)" ::: "memory");
    else             asm volatile("s_waitcnt vmcnt(0)" ::: "memory");
    asm volatile("s_barrier" ::: "memory");   // tile kt landed everywhere;
    issue(kt + 2);                            // slot (kt-1)%3 free to overwrite

    if (active) {
      const char* slot = wslots + (kt % 3) * SLOTB;
      bf16x8 bfrag;
#pragma unroll
      for (int i = 0; i < 8; ++i) {
        const float w = *(const float*)(slot + (uint32_t)(g * 8 + i) * PITCH +
                                        (uint32_t)(wave * 16 + col) * 4u);
        bfrag[i] = (__bf16)w;
      }
      const int kb = kt * 32 + g * 8;
#pragma unroll
      for (int mt = 0; mt < MT; ++mt) {
        const int m = mt * 16 + col;
        const uint32_t ab = ASWZ
            ? (uint32_t)m * HROWB + (((uint32_t)(kb * 2)) ^ (((uint32_t)m & 7u) << 4))
            : (uint32_t)m * XPITCHB + (uint32_t)(kb * 2);
        const bf16x8 afrag = *(const bf16x8*)(A + ab);
        acc[mt] = __builtin_amdgcn_mfma_f32_16x16x32_bf16(afrag, bfrag, acc[mt], 0, 0, 0);
      }
    }
  }

  // epilogue: bias (+relu -> global h bf16 | even-col fp32 -> out)
  if (active) {
    const int n = nc0 + wave * 16 + col;
    const float bias = bg[n];
#pragma unroll
    for (int mt = 0; mt < MT; ++mt) {
#pragma unroll
      for (int r = 0; r < 4; ++r) {
        float v = acc[mt][r] + bias;
        const int m = mt * 16 + g * 4 + r;
        if (RELU) {
          v = v > 0.f ? v : 0.f;
          hg[m * HID + n] = (__bf16)v;
        } else if ((n & 1) == 0) {
          const unsigned long long oi =
              (unsigned long long)m * (NCH * OUTS) + (unsigned long long)(n >> 1);
          if (oi < out_sz) outg[oi] = v;
        }
      }
    }
  }
}

// Stage h[c] (64 x 512B global) -> LDS with the (m&7)<<4 XOR swizzle.
__device__ __forceinline__ void stage_h(const __bf16* __restrict__ hg,
                                        char* __restrict__ hbuf, int tid) {
  const int m  = tid >> 3;
  const int qb = (tid & 7) * 64;
#pragma unroll
  for (int i = 0; i < 4; ++i) {
    const uint32_t cb = qb + i * 16;
    uint4 v = *(const uint4*)((const char*)hg + (uint32_t)m * HROWB + cb);
    *(uint4*)(hbuf + (uint32_t)m * HROWB + (cb ^ (((uint32_t)m & 7u) << 4))) = v;
  }
  __syncthreads();
}

__global__ __launch_bounds__(BLOCK) void k_layer1(
    const float* __restrict__ ue,   const float* __restrict__ view,
    const float* __restrict__ feat, const int*   __restrict__ ids,
    const float* __restrict__ W1, const float* __restrict__ b1,
    __bf16* __restrict__ h1g)
{
  extern __shared__ __attribute__((aligned(16))) char smem[];
  char* xbuf   = smem;               // 21504 B
  char* wslots = smem + 21504;       // 3 x 16 KB

  const int c  = blockIdx.x >> 1;
  const int nh = blockIdx.x & 1;
  const int tid = threadIdx.x, wave = tid >> 6, lane = tid & 63;

  for (int idx = tid; idx < BATCH * (XPITCHB / 2); idx += BLOCK) {
    const int m = idx / (XPITCHB / 2);
    const int k = idx - m * (XPITCHB / 2);
    float v = 0.0f;
    if (k < 3)         v = ue[m * 3 + k];
    else if (k < 6)    v = view[m * 3 + (k - 3)];
    else if (k < 134)  v = feat[m * 128 + (k - 6)];
    else if (k == 134) v = ((float)ids[m] - 1.0f) * (1.0f / 63.0f);
    *(__bf16*)(xbuf + (uint32_t)m * XPITCHB + 2u * (uint32_t)k) = (__bf16)v;
  }
  __syncthreads();

  chunk_pipe<IN_K, 5, HID, 128, false, true>(
      xbuf, W1 + (size_t)c * IN_K * HID, b1 + (size_t)c * HID,
      h1g + (size_t)c * BATCH * HID, nullptr, 0, nh * 128, wslots, wave, lane);
}

__global__ __launch_bounds__(BLOCK) void k_layer2(
    const __bf16* __restrict__ h1g,
    const float* __restrict__ W2, const float* __restrict__ b2,
    __bf16* __restrict__ h2g)
{
  extern __shared__ __attribute__((aligned(16))) char smem[];
  char* hbuf   = smem;               // 32 KB
  char* wslots = smem + 32768;       // 3 x 16 KB

  const int c  = blockIdx.x >> 1;
  const int nh = blockIdx.x & 1;
  const int tid = threadIdx.x, wave = tid >> 6, lane = tid & 63;

  stage_h(h1g + (size_t)c * BATCH * HID, hbuf, tid);

  chunk_pipe<HID, 8, HID, 128, true, true>(
      hbuf, W2 + (size_t)c * HID * HID, b2 + (size_t)c * HID,
      h2g + (size_t)c * BATCH * HID, nullptr, 0, nh * 128, wslots, wave, lane);
}

__global__ __launch_bounds__(BLOCK) void k_layer3(
    const __bf16* __restrict__ h2g,
    const float* __restrict__ W3, const float* __restrict__ b3,
    float* __restrict__ out, unsigned long long out_sz)
{
  extern __shared__ __attribute__((aligned(16))) char smem[];
  char* hbuf   = smem;               // 32 KB
  char* wslots = smem + 32768;       // 3 x 16 KB

  const int c  = blockIdx.x >> 1;
  const int nh = blockIdx.x & 1;
  const int tid = threadIdx.x, wave = tid >> 6, lane = tid & 63;

  stage_h(h2g + (size_t)c * BATCH * HID, hbuf, tid);

  const float* W3c = W3 + (size_t)c * HID * OUTN;
  const float* b3c = b3 + (size_t)c * OUTN;
  float* outc = out + (size_t)c * OUTS;

  if (nh == 0) {
    chunk_pipe<HID, 8, OUTN, 128, true, false>(hbuf, W3c, b3c, nullptr, outc,
                                               out_sz, 0,   wslots, wave, lane);
    chunk_pipe<HID, 8, OUTN, 128, true, false>(hbuf, W3c, b3c, nullptr, outc,
                                               out_sz, 128, wslots, wave, lane);
    chunk_pipe<HID, 8, OUTN, 128, true, false>(hbuf, W3c, b3c, nullptr, outc,
                                               out_sz, 256, wslots, wave, lane);
  } else {
    chunk_pipe<HID, 8, OUTN, 128, true, false>(hbuf, W3c, b3c, nullptr, outc,
                                               out_sz, 384, wslots, wave, lane);
    chunk_pipe<HID, 8, OUTN, 128, true, false>(hbuf, W3c, b3c, nullptr, outc,
                                               out_sz, 512, wslots, wave, lane);
    chunk_pipe<HID, 8, OUTN, 128, true, false>(hbuf, W3c, b3c, nullptr, outc,
                                               out_sz, 640, wslots, wave, lane);
    chunk_pipe<HID, 8, OUTN, 48, true, false>(hbuf, W3c, b3c, nullptr, outc,
                                              out_sz, 768, wslots, wave, lane);
  }
}

extern "C" void kernel_launch(void* const* d_in, const int* in_sizes, int n_in,
                              void* d_out, int out_size, void* d_ws, size_t ws_size,
                              hipStream_t stream) {
  const float* ue   = (const float*)d_in[0];
  const float* view = (const float*)d_in[1];
  const float* feat = (const float*)d_in[2];
  const int*   ids  = (const int*)d_in[3];
  const float* W1   = (const float*)d_in[4];
  const float* b1   = (const float*)d_in[5];
  const float* W2   = (const float*)d_in[6];
  const float* b2   = (const float*)d_in[7];
  const float* W3   = (const float*)d_in[8];
  const float* b3   = (const float*)d_in[9];
  float* out = (float*)d_out;

  // d_ws: h1 then h2, each 256ch x 64 x 256 bf16 = 8 MB.
  __bf16* h1g = (__bf16*)d_ws;
  __bf16* h2g = h1g + (size_t)NCH * BATCH * HID;

  const int smem1 = 21504 + WRINGB;   // 70656
  const int smem2 = 32768 + WRINGB;   // 81920 -> 2 blocks/CU = 160 KB exactly

  hipFuncSetAttribute(reinterpret_cast<const void*>(k_layer1),
                      hipFuncAttributeMaxDynamicSharedMemorySize, smem1);
  hipFuncSetAttribute(reinterpret_cast<const void*>(k_layer2),
                      hipFuncAttributeMaxDynamicSharedMemorySize, smem2);
  hipFuncSetAttribute(reinterpret_cast<const void*>(k_layer3),
                      hipFuncAttributeMaxDynamicSharedMemorySize, smem2);

  hipLaunchKernelGGL(k_layer1, dim3(NCH * 2), dim3(BLOCK), smem1, stream,
                     ue, view, feat, ids, W1, b1, h1g);
  hipLaunchKernelGGL(k_layer2, dim3(NCH * 2), dim3(BLOCK), smem2, stream,
                     h1g, W2, b2, h2g);
  hipLaunchKernelGGL(k_layer3, dim3(NCH * 2), dim3(BLOCK), smem2, stream,
                     h2g, W3, b3, out, (unsigned long long)out_size);
}

// Round 21
// 79.237 us; speedup vs baseline: 1.3705x; 1.3705x over previous
//
#include <hip/hip_runtime.h>
#include <hip/hip_bf16.h>
#include <stdint.h>

// RadianceNetwork: 256 independent channel MLPs, B=64.
//   x  = concat(ue[3], view[3], feat[128], nid[1])  -> [64, 135]
//   h1 = relu(x @ W1[c] + b1[c])                    -> [64, 256]
//   h2 = relu(h1 @ W2[c] + b2[c])                   -> [64, 256]
//   o  = h2 @ W3[c] + b3[c]                         -> [64, 816]
// OUTPUT: real components only, fp32 [64][256][408] (R0-R5 forensics).
//
// R21 = R16 (84us best) with three in-place fixes:
//  1. FLAT per-layer pipeline: no chunk-seam drains (chunks share the A
//     buffer); drains only at the 3 layer seams. Uniform 1 DMA/wave/tile.
//  2. Source-XOR-swizzled DMA (pre-swizzle per-lane GLOBAL address, LDS
//     dest stays linear): n-quad q of row r stored at unit q^((r>>3)&3).
//     ds_read_b32 B-frag reads become conflict-free (was 4-way).
//  3. Depth 3 (4 slots): issue tile tau+3 at step tau; steady vmcnt(2),
//     graduated 2/1/0 tail. In-order vmcnt retirement makes vmcnt(2) safe
//     even with epilogue stores in the queue.
// Geometry (R16): 16 waves x 1024 thr, grid 256 (1 block/CU); wave w owns
// n-tile w&7 of the 128-col chunk, m-half w>>3 (MT=2).
// LDS: h1 32K + {x|h2} 32K + ring 4x16K = 128 KB dynamic.

#define NCH    256
#define BATCH  64
#define IN_K   135
#define HID    256
#define OUTN   816
#define OUTS   408
#define XPITCHB 336   // x row bytes (168 bf16; zero-padded k in [135,168))
#define HROWB   512   // h row bytes (256 bf16, XOR-swizzled)
#define NWAVES 16
#define BLOCK  1024
#define SLOTB  16384  // ring slot: 32 k-rows x 128 n-cols fp32
#define SMEM_BYTES (128 * 1024)

typedef __bf16 bf16x8 __attribute__((ext_vector_type(8)));
typedef float  f32x4  __attribute__((ext_vector_type(4)));
typedef const __attribute__((address_space(1))) void* gas_t;
typedef __attribute__((address_space(3))) void*       las_t;

// One layer as ONE flat pipeline over (chunk, kt) tiles.
// MFMA 16x16x32 bf16 (m89 layouts). Ring slot: fp32 rows of 512B; row r
// holds quads in XOR order: unit u = q ^ ((r>>3)&3). Wave w's DMA covers
// rows 2w,2w+1 (dest linear = slot + w*1024 + lane*16; src quad pre-swz).
template<int K, int KT, int NSRC, int NCHUNK, int LASTCW, bool ASWZ, bool RELU>
__device__ __forceinline__ void layer_flat(
    const char*  __restrict__ A,     // LDS activations (x or swizzled h)
    const float* __restrict__ Wg,    // [K][NSRC] weights, channel base
    const float* __restrict__ bg,    // bias, channel base
    char*        __restrict__ Hout,  // LDS out (RELU), swizzled pitch 512B
    float*       __restrict__ Gout,  // global out base (+c*OUTS)
    unsigned long long out_sz,
    char* __restrict__ ring,         // 4 x 16 KB
    int wave, int lane)
{
  constexpr int TOT = NCHUNK * KT;
  const int col = lane & 15;
  const int g   = lane >> 4;
  const int nt  = wave & 7;          // n-tile within 128-col chunk
  const int mh  = wave >> 3;         // m-half
  const int sw  = (wave >> 2) & 3;   // DMA source swizzle (wave-uniform)

  // per-chunk bias preload (static indexing via full unroll below)
  float bs[NCHUNK];
#pragma unroll
  for (int ci = 0; ci < NCHUNK; ++ci) {
    const bool act = (nt * 16) < ((ci == NCHUNK - 1) ? LASTCW : 128);
    bs[ci] = act ? bg[ci * 128 + nt * 16 + col] : 0.0f;
  }

  auto issue = [&](int ci, int kt) {
    if (ci < NCHUNK) {
      const int t = ci * KT + kt;
      char* dst = ring + (t & 3) * SLOTB + wave * 1024 + lane * 16;
      int k = kt * 32 + 2 * wave + (lane >> 5);
      if (K % 32 != 0) k = (k < K) ? k : (K - 1);     // L1 tail: finite clamp
      size_t off = (size_t)k * NSRC + ci * 128 + (size_t)(((lane & 31) ^ sw) << 2);
      if (LASTCW < 128) {                             // L3 tail: stay in W[c]
        const size_t mx = (size_t)K * NSRC - 4;
        off = (off < mx) ? off : mx;
      }
      __builtin_amdgcn_global_load_lds((gas_t)(Wg + off), (las_t)dst, 16, 0, 0);
    }
  };

  // prologue: 3 tiles in flight (KT >= 5 so all in chunk 0)
  issue(0, 0); issue(0, 1); issue(0, 2);
  int ci_n = 0, kt_n = 3;

  f32x4 acc[2] = {};
  int tau = 0;

#pragma unroll
  for (int ci = 0; ci < NCHUNK; ++ci) {
    const bool act = (nt * 16) < ((ci == NCHUNK - 1) ? LASTCW : 128);
#pragma unroll
    for (int kt = 0; kt < KT; ++kt, ++tau) {
      const int rem = TOT - 1 - tau;                  // compile-time
      if (rem >= 2)      asm volatile("s_waitcnt vmcnt(2)" ::: "memory");
      else if (rem == 1) asm volatile("s_waitcnt vmcnt(1)" ::: "memory");
      else               asm volatile("s_waitcnt vmcnt(0)" ::: "memory");
      asm volatile("s_barrier" ::: "memory");         // tile tau landed everywhere
      issue(ci_n, kt_n);                              // slot (tau+3)&3 = (tau-1)&3: free
      if (++kt_n == KT) { kt_n = 0; ++ci_n; }

      if (act) {
        const char* slot = ring + (tau & 3) * SLOTB;
        bf16x8 bfrag;
#pragma unroll
        for (int i = 0; i < 8; ++i) {
          // row r = g*8+i has swizzle s_r = (r>>3)&3 = g; quad q = nt*4+(col>>2)
          const uint32_t q = (uint32_t)(nt * 4 + (col >> 2));
          const float w = *(const float*)(slot + (uint32_t)(g * 8 + i) * 512u +
                                          ((q ^ (uint32_t)g) * 16u) +
                                          (uint32_t)(col & 3) * 4u);
          bfrag[i] = (__bf16)w;
        }
        const int kb = kt * 32 + g * 8;
#pragma unroll
        for (int mt = 0; mt < 2; ++mt) {
          const int m = mh * 32 + mt * 16 + col;
          const uint32_t ab = ASWZ
              ? (uint32_t)m * HROWB + (((uint32_t)(kb * 2)) ^ (((uint32_t)m & 7u) << 4))
              : (uint32_t)m * XPITCHB + (uint32_t)(kb * 2);
          const bf16x8 afrag = *(const bf16x8*)(A + ab);
          acc[mt] = __builtin_amdgcn_mfma_f32_16x16x32_bf16(afrag, bfrag, acc[mt], 0, 0, 0);
        }
      }

      if (kt == KT - 1) {          // chunk epilogue
        if (act) {
          const int n = ci * 128 + nt * 16 + col;
          const float bias = bs[ci];
#pragma unroll
          for (int mt = 0; mt < 2; ++mt) {
#pragma unroll
            for (int r = 0; r < 4; ++r) {
              float v = acc[mt][r] + bias;
              const int m = mh * 32 + mt * 16 + g * 4 + r;
              if (RELU) {
                v = v > 0.f ? v : 0.f;
                *(__bf16*)(Hout + (uint32_t)m * HROWB +
                           (((uint32_t)(n * 2)) ^ (((uint32_t)m & 7u) << 4))) = (__bf16)v;
              } else if ((n & 1) == 0) {
                const unsigned long long oi =
                    (unsigned long long)m * (NCH * OUTS) + (unsigned long long)(n >> 1);
                if (oi < out_sz) Gout[oi] = v;
              }
            }
          }
        }
#pragma unroll
        for (int mt = 0; mt < 2; ++mt) acc[mt] = (f32x4){0.f, 0.f, 0.f, 0.f};
      }
    }
  }
}

__global__ __launch_bounds__(BLOCK) void radiance_mlp_kernel(
    const float* __restrict__ ue,   const float* __restrict__ view,
    const float* __restrict__ feat, const int*   __restrict__ ids,
    const float* __restrict__ W1, const float* __restrict__ b1,
    const float* __restrict__ W2, const float* __restrict__ b2,
    const float* __restrict__ W3, const float* __restrict__ b3,
    float* __restrict__ out, unsigned long long out_sz)
{
  extern __shared__ __attribute__((aligned(16))) char smem[];
  char* buf0 = smem;                 // h1: 32 KB (swizzled pitch 512B)
  char* buf1 = smem + 32768;         // x (pitch 336B) then h2: 32 KB
  char* ring = smem + 65536;         // 4 x 16 KB W ring

  const int c    = blockIdx.x;
  const int tid  = threadIdx.x;
  const int wave = tid >> 6;
  const int lane = tid & 63;

  // Stage input x -> bf16 in buf1 (pitch 336B), zero-pad k in [135,168).
  for (int idx = tid; idx < BATCH * (XPITCHB / 2); idx += BLOCK) {
    const int m = idx / (XPITCHB / 2);
    const int k = idx - m * (XPITCHB / 2);
    float v = 0.0f;
    if (k < 3)         v = ue[m * 3 + k];
    else if (k < 6)    v = view[m * 3 + (k - 3)];
    else if (k < 134)  v = feat[m * 128 + (k - 6)];
    else if (k == 134) v = ((float)ids[m] - 1.0f) * (1.0f / 63.0f);
    *(__bf16*)(buf1 + (uint32_t)m * XPITCHB + 2u * (uint32_t)k) = (__bf16)v;
  }
  // raw lgkm barrier (NOT __syncthreads: that would also drain vmcnt later)
  asm volatile("s_waitcnt lgkmcnt(0)" ::: "memory");
  asm volatile("s_barrier" ::: "memory");

  // L1: x(buf1) -> h1(buf0).  K=135, 2 chunks x 5 k-tiles, flat.
  layer_flat<IN_K, 5, HID, 2, 128, false, true>(
      buf1, W1 + (size_t)c * IN_K * HID, b1 + (size_t)c * HID,
      buf0, nullptr, 0, ring, wave, lane);
  asm volatile("s_waitcnt lgkmcnt(0)" ::: "memory");
  asm volatile("s_barrier" ::: "memory");

  // L2: h1(buf0) -> h2(buf1).  K=256, 2 chunks x 8 k-tiles, flat.
  layer_flat<HID, 8, HID, 2, 128, true, true>(
      buf0, W2 + (size_t)c * HID * HID, b2 + (size_t)c * HID,
      buf1, nullptr, 0, ring, wave, lane);
  asm volatile("s_waitcnt lgkmcnt(0)" ::: "memory");
  asm volatile("s_barrier" ::: "memory");

  // L3: h2(buf1) -> out.  K=256, 7 chunks (6x128 + 48) x 8 k-tiles, flat.
  layer_flat<HID, 8, OUTN, 7, 48, true, false>(
      buf1, W3 + (size_t)c * HID * OUTN, b3 + (size_t)c * OUTN,
      nullptr, out + (size_t)c * OUTS, out_sz, ring, wave, lane);
}

extern "C" void kernel_launch(void* const* d_in, const int* in_sizes, int n_in,
                              void* d_out, int out_size, void* d_ws, size_t ws_size,
                              hipStream_t stream) {
  const float* ue   = (const float*)d_in[0];
  const float* view = (const float*)d_in[1];
  const float* feat = (const float*)d_in[2];
  const int*   ids  = (const int*)d_in[3];
  const float* W1   = (const float*)d_in[4];
  const float* b1   = (const float*)d_in[5];
  const float* W2   = (const float*)d_in[6];
  const float* b2   = (const float*)d_in[7];
  const float* W3   = (const float*)d_in[8];
  const float* b3   = (const float*)d_in[9];
  float* out = (float*)d_out;

  // Host-side attribute set (not a stream op; graph-capture-safe, idempotent).
  hipFuncSetAttribute(reinterpret_cast<const void*>(radiance_mlp_kernel),
                      hipFuncAttributeMaxDynamicSharedMemorySize, SMEM_BYTES);

  hipLaunchKernelGGL(radiance_mlp_kernel, dim3(NCH), dim3(BLOCK), SMEM_BYTES,
                     stream, ue, view, feat, ids, W1, b1, W2, b2, W3, b3,
                     out, (unsigned long long)out_size);
}

// Round 22
// 78.641 us; speedup vs baseline: 1.3809x; 1.0076x over previous
//
#include <hip/hip_runtime.h>
#include <hip/hip_bf16.h>
#include <stdint.h>

// RadianceNetwork: 256 independent channel MLPs, B=64.
//   x  = concat(ue[3], view[3], feat[128], nid[1])  -> [64, 135]
//   h1 = relu(x @ W1[c] + b1[c])                    -> [64, 256]
//   h2 = relu(h1 @ W2[c] + b2[c])                   -> [64, 256]
//   o  = h2 @ W3[c] + b3[c]                         -> [64, 816]
// OUTPUT: real components only, fp32 [64][256][408] (R0-R5 forensics).
//
// R22 = R21 (79.2us) + two fixes:
//  1. DEPTH 5 / RING 6 (LDS 160KB): 80KB in flight per CU (was 48KB).
//     R21 analysis: 17GB/s/CU at 48KB in flight => loaded latency ~2.8us;
//     fabric headroom proven by fillBuffer @7TB/s. Little's law: more bytes.
//  2. CORRECT B-swizzle: R21's quad-XOR left SQ_LDS_BANK_CONFLICT bit-
//     identical to R16 (7.57M) - XOR of quad low bits permutes within the
//     same 16-bank group. Now XOR the 64B SEGMENT index (qq ^ (sw<<2)) on
//     the DMA source; read at (nt^g)*64: opposite-parity g-groups hit
//     opposite 16-bank halves -> 2 lanes/bank = free.
// Geometry (R16/R21): 16 waves x 1024 thr, grid 256 (1 block/CU); wave w:
// n-tile w&7 of 128-col chunk, m-half w>>3 (MT=2). Flat per-layer pipeline,
// raw s_barrier + graduated counted vmcnt; drains only at 3 layer seams.
// LDS: h1 32K + {x|h2} 32K + ring 6x16K = 160 KB dynamic.

#define NCH    256
#define BATCH  64
#define IN_K   135
#define HID    256
#define OUTN   816
#define OUTS   408
#define XPITCHB 336   // x row bytes (168 bf16; zero-padded k in [135,168))
#define HROWB   512   // h row bytes (256 bf16, XOR-swizzled)
#define NWAVES 16
#define BLOCK  1024
#define SLOTB  16384  // ring slot: 32 k-rows x 128 n-cols fp32
#define RING   6
#define DEPTH  5
#define SMEM_BYTES (160 * 1024)

typedef __bf16 bf16x8 __attribute__((ext_vector_type(8)));
typedef float  f32x4  __attribute__((ext_vector_type(4)));
typedef const __attribute__((address_space(1))) void* gas_t;
typedef __attribute__((address_space(3))) void*       las_t;

// One layer as ONE flat pipeline over (chunk, kt) tiles.
// MFMA 16x16x32 bf16 (m89 layouts). Ring slot: fp32 rows of 512B; row r
// stores logical 64B-segment s at physical s ^ ((r>>3)&3) (src pre-swizzle,
// LDS dest linear). Wave w's DMA covers rows 2w,2w+1.
template<int K, int KT, int NSRC, int NCHUNK, int LASTCW, bool ASWZ, bool RELU>
__device__ __forceinline__ void layer_flat(
    const char*  __restrict__ A,     // LDS activations (x or swizzled h)
    const float* __restrict__ Wg,    // [K][NSRC] weights, channel base
    const float* __restrict__ bg,    // bias, channel base
    char*        __restrict__ Hout,  // LDS out (RELU), swizzled pitch 512B
    float*       __restrict__ Gout,  // global out base (+c*OUTS)
    unsigned long long out_sz,
    char* __restrict__ ring,         // RING x 16 KB
    int wave, int lane)
{
  constexpr int TOT = NCHUNK * KT;
  const int col = lane & 15;
  const int g   = lane >> 4;
  const int nt  = wave & 7;          // n-tile within 128-col chunk
  const int mh  = wave >> 3;         // m-half
  const int sw  = (wave >> 2) & 3;   // segment swizzle (== (row>>3)&3)

  // per-chunk bias preload (static indexing via full unroll below)
  float bs[NCHUNK];
#pragma unroll
  for (int ci = 0; ci < NCHUNK; ++ci) {
    const bool act = (nt * 16) < ((ci == NCHUNK - 1) ? LASTCW : 128);
    bs[ci] = act ? bg[ci * 128 + nt * 16 + col] : 0.0f;
  }

  auto issue = [&](int t) {
    if (t < TOT) {
      const int ci = t / KT;
      const int kt = t - ci * KT;
      char* dst = ring + (t % RING) * SLOTB + wave * 1024 + lane * 16;
      int k = kt * 32 + 2 * wave + (lane >> 5);
      if (K % 32 != 0) k = (k < K) ? k : (K - 1);     // L1 tail: finite clamp
      const int qq = lane & 31;                        // row-local 16B quad
      size_t off = (size_t)k * NSRC + ci * 128 +
                   (size_t)((qq ^ (sw << 2)) << 2);    // segment-XOR source
      if (LASTCW < 128) {                              // L3 tail: stay in W[c]
        const size_t mx = (size_t)K * NSRC - 4;
        off = (off < mx) ? off : mx;
      }
      __builtin_amdgcn_global_load_lds((gas_t)(Wg + off), (las_t)dst, 16, 0, 0);
    }
  };

  // prologue: DEPTH tiles in flight
  issue(0); issue(1); issue(2); issue(3); issue(4);

  f32x4 acc[2] = {};
  int tau = 0;

#pragma unroll
  for (int ci = 0; ci < NCHUNK; ++ci) {
    const bool act = (nt * 16) < ((ci == NCHUNK - 1) ? LASTCW : 128);
#pragma unroll
    for (int kt = 0; kt < KT; ++kt, ++tau) {
      const int rem = TOT - 1 - tau;                  // compile-time
      if (rem >= 4)      asm volatile("s_waitcnt vmcnt(4)" ::: "memory");
      else if (rem == 3) asm volatile("s_waitcnt vmcnt(3)" ::: "memory");
      else if (rem == 2) asm volatile("s_waitcnt vmcnt(2)" ::: "memory");
      else if (rem == 1) asm volatile("s_waitcnt vmcnt(1)" ::: "memory");
      else               asm volatile("s_waitcnt vmcnt(0)" ::: "memory");
      asm volatile("s_barrier" ::: "memory");         // tile tau landed everywhere
      issue(tau + DEPTH);                // slot (tau+5)%6 = (tau-1)%6: free

      if (act) {
        const char* slot = ring + (tau % RING) * SLOTB;
        bf16x8 bfrag;
#pragma unroll
        for (int i = 0; i < 8; ++i) {
          // row r = g*8+i: swizzle (r>>3)&3 == g; logical segment nt
          const float w = *(const float*)(slot + (uint32_t)(g * 8 + i) * 512u +
                                          (((uint32_t)(nt ^ g)) << 6) +
                                          (uint32_t)col * 4u);
          bfrag[i] = (__bf16)w;
        }
        const int kb = kt * 32 + g * 8;
#pragma unroll
        for (int mt = 0; mt < 2; ++mt) {
          const int m = mh * 32 + mt * 16 + col;
          const uint32_t ab = ASWZ
              ? (uint32_t)m * HROWB + (((uint32_t)(kb * 2)) ^ (((uint32_t)m & 7u) << 4))
              : (uint32_t)m * XPITCHB + (uint32_t)(kb * 2);
          const bf16x8 afrag = *(const bf16x8*)(A + ab);
          acc[mt] = __builtin_amdgcn_mfma_f32_16x16x32_bf16(afrag, bfrag, acc[mt], 0, 0, 0);
        }
      }

      if (kt == KT - 1) {          // chunk epilogue
        if (act) {
          const int n = ci * 128 + nt * 16 + col;
          const float bias = bs[ci];
#pragma unroll
          for (int mt = 0; mt < 2; ++mt) {
#pragma unroll
            for (int r = 0; r < 4; ++r) {
              float v = acc[mt][r] + bias;
              const int m = mh * 32 + mt * 16 + g * 4 + r;
              if (RELU) {
                v = v > 0.f ? v : 0.f;
                *(__bf16*)(Hout + (uint32_t)m * HROWB +
                           (((uint32_t)(n * 2)) ^ (((uint32_t)m & 7u) << 4))) = (__bf16)v;
              } else if ((n & 1) == 0) {
                const unsigned long long oi =
                    (unsigned long long)m * (NCH * OUTS) + (unsigned long long)(n >> 1);
                if (oi < out_sz) Gout[oi] = v;
              }
            }
          }
        }
#pragma unroll
        for (int mt = 0; mt < 2; ++mt) acc[mt] = (f32x4){0.f, 0.f, 0.f, 0.f};
      }
    }
  }
}

__global__ __launch_bounds__(BLOCK) void radiance_mlp_kernel(
    const float* __restrict__ ue,   const float* __restrict__ view,
    const float* __restrict__ feat, const int*   __restrict__ ids,
    const float* __restrict__ W1, const float* __restrict__ b1,
    const float* __restrict__ W2, const float* __restrict__ b2,
    const float* __restrict__ W3, const float* __restrict__ b3,
    float* __restrict__ out, unsigned long long out_sz)
{
  extern __shared__ __attribute__((aligned(16))) char smem[];
  char* buf0 = smem;                 // h1: 32 KB (swizzled pitch 512B)
  char* buf1 = smem + 32768;         // x (pitch 336B) then h2: 32 KB
  char* ring = smem + 65536;         // 6 x 16 KB W ring

  const int c    = blockIdx.x;
  const int tid  = threadIdx.x;
  const int wave = tid >> 6;
  const int lane = tid & 63;

  // Stage input x -> bf16 in buf1 (pitch 336B), zero-pad k in [135,168).
  for (int idx = tid; idx < BATCH * (XPITCHB / 2); idx += BLOCK) {
    const int m = idx / (XPITCHB / 2);
    const int k = idx - m * (XPITCHB / 2);
    float v = 0.0f;
    if (k < 3)         v = ue[m * 3 + k];
    else if (k < 6)    v = view[m * 3 + (k - 3)];
    else if (k < 134)  v = feat[m * 128 + (k - 6)];
    else if (k == 134) v = ((float)ids[m] - 1.0f) * (1.0f / 63.0f);
    *(__bf16*)(buf1 + (uint32_t)m * XPITCHB + 2u * (uint32_t)k) = (__bf16)v;
  }
  // raw lgkm barrier (NOT __syncthreads: that would also drain vmcnt later)
  asm volatile("s_waitcnt lgkmcnt(0)" ::: "memory");
  asm volatile("s_barrier" ::: "memory");

  // L1: x(buf1) -> h1(buf0).  K=135, 2 chunks x 5 k-tiles, flat.
  layer_flat<IN_K, 5, HID, 2, 128, false, true>(
      buf1, W1 + (size_t)c * IN_K * HID, b1 + (size_t)c * HID,
      buf0, nullptr, 0, ring, wave, lane);
  asm volatile("s_waitcnt lgkmcnt(0)" ::: "memory");
  asm volatile("s_barrier" ::: "memory");

  // L2: h1(buf0) -> h2(buf1).  K=256, 2 chunks x 8 k-tiles, flat.
  layer_flat<HID, 8, HID, 2, 128, true, true>(
      buf0, W2 + (size_t)c * HID * HID, b2 + (size_t)c * HID,
      buf1, nullptr, 0, ring, wave, lane);
  asm volatile("s_waitcnt lgkmcnt(0)" ::: "memory");
  asm volatile("s_barrier" ::: "memory");

  // L3: h2(buf1) -> out.  K=256, 7 chunks (6x128 + 48) x 8 k-tiles, flat.
  layer_flat<HID, 8, OUTN, 7, 48, true, false>(
      buf1, W3 + (size_t)c * HID * OUTN, b3 + (size_t)c * OUTN,
      nullptr, out + (size_t)c * OUTS, out_sz, ring, wave, lane);
}

extern "C" void kernel_launch(void* const* d_in, const int* in_sizes, int n_in,
                              void* d_out, int out_size, void* d_ws, size_t ws_size,
                              hipStream_t stream) {
  const float* ue   = (const float*)d_in[0];
  const float* view = (const float*)d_in[1];
  const float* feat = (const float*)d_in[2];
  const int*   ids  = (const int*)d_in[3];
  const float* W1   = (const float*)d_in[4];
  const float* b1   = (const float*)d_in[5];
  const float* W2   = (const float*)d_in[6];
  const float* b2   = (const float*)d_in[7];
  const float* W3   = (const float*)d_in[8];
  const float* b3   = (const float*)d_in[9];
  float* out = (float*)d_out;

  // Host-side attribute set (not a stream op; graph-capture-safe, idempotent).
  hipFuncSetAttribute(reinterpret_cast<const void*>(radiance_mlp_kernel),
                      hipFuncAttributeMaxDynamicSharedMemorySize, SMEM_BYTES);

  hipLaunchKernelGGL(radiance_mlp_kernel, dim3(NCH), dim3(BLOCK), SMEM_BYTES,
                     stream, ue, view, feat, ids, W1, b1, W2, b2, W3, b3,
                     out, (unsigned long long)out_size);
}